// Round 9
// baseline (419.250 us; speedup 1.0000x reference)
//
#include <hip/hip_runtime.h>
#include <hip/hip_bf16.h>
#include <math.h>

#define N_NODES 50000
#define NEDGE 1600000
#define BN_EPS 1e-5f
#define NP 8            // XCD partitions
#define PR 6250         // rows per partition (8*6250 = 50000)
#define NCHUNK 196      // edge chunks (196*2048 int4 >= 400000)
#define HB (NP * NCHUNK)  // 1568 partitioned-scan blocks
#define G1_BLOCKS 1563  // ceil(50000/32) gemm1 tiles
#define GB 2048         // gather grid blocks (256 per partition)
#define FB 512          // final partial blocks

__device__ inline float bf2f(ushort u) {
  union { unsigned i; float f; } v;
  v.i = ((unsigned)u) << 16;
  return v.f;
}
__device__ inline ushort f2bf(float x) {
  __hip_bfloat16 b = __float2bfloat16(x);
  return *(ushort*)&b;
}

// ---------------------------------------------------------------------------
// Fused: blocks [0,HB) -> partitioned histogram (XCD-local atomics);
//        blocks [HB, HB+G1_BLOCKS) -> GEMM1 32-row tile (f32 math, bf16 out).
// ---------------------------------------------------------------------------
__global__ __launch_bounds__(256) void hist_gemm1_kernel(
    const int4* __restrict__ row4, int* __restrict__ cnt,
    const float4* __restrict__ X4, const float4* __restrict__ W4,
    ushort* __restrict__ C) {
  __shared__ float4 sW[32 * 32];   // 16KB (32-k chunk of W)
  __shared__ float4 sX[32 * 32];   // 16KB
  const int t = threadIdx.x;
  const int bid = blockIdx.x;

  if (bid < HB) {  // ---- partitioned histogram ----
    const int p = bid & 7;
    const int chunk = bid >> 3;
    const int lo = p * PR;
    for (int i = t; i < 2048; i += 256) {
      int idx = chunk * 2048 + i;
      if (idx < NEDGE / 4) {
        int4 r = row4[idx];
        if ((unsigned)(r.x - lo) < PR) atomicAdd(&cnt[r.x], 1);
        if ((unsigned)(r.y - lo) < PR) atomicAdd(&cnt[r.y], 1);
        if ((unsigned)(r.z - lo) < PR) atomicAdd(&cnt[r.z], 1);
        if ((unsigned)(r.w - lo) < PR) atomicAdd(&cnt[r.w], 1);
      }
    }
    return;
  }

  // ---- gemm1 part ----
  float* Xl = (float*)sX;
  const int r0 = (bid - HB) * 32;

  for (int i = t; i < 1024; i += 256) {
    int rr = i >> 5;
    int r = r0 + rr;
    sX[i] = (r < N_NODES) ? X4[(long)r * 32 + (i & 31)]
                          : make_float4(0.f, 0.f, 0.f, 0.f);
  }

  const int tx = t & 31;
  const int ty = t >> 5;
  float acc[4][4] = {{0.f}};

  for (int kt = 0; kt < 4; ++kt) {   // four 32-k chunks
    __syncthreads();
    for (int i = t; i < 1024; i += 256) sW[i] = W4[kt * 1024 + i];
    __syncthreads();
    const int kbase = kt * 32;
#pragma unroll 8
    for (int kk = 0; kk < 32; ++kk) {
      float4 wv = sW[kk * 32 + tx];
      float x0 = Xl[(ty * 4 + 0) * 128 + kbase + kk];
      float x1 = Xl[(ty * 4 + 1) * 128 + kbase + kk];
      float x2 = Xl[(ty * 4 + 2) * 128 + kbase + kk];
      float x3 = Xl[(ty * 4 + 3) * 128 + kbase + kk];
      acc[0][0] += x0 * wv.x; acc[0][1] += x0 * wv.y;
      acc[0][2] += x0 * wv.z; acc[0][3] += x0 * wv.w;
      acc[1][0] += x1 * wv.x; acc[1][1] += x1 * wv.y;
      acc[1][2] += x1 * wv.z; acc[1][3] += x1 * wv.w;
      acc[2][0] += x2 * wv.x; acc[2][1] += x2 * wv.y;
      acc[2][2] += x2 * wv.z; acc[2][3] += x2 * wv.w;
      acc[3][0] += x3 * wv.x; acc[3][1] += x3 * wv.y;
      acc[3][2] += x3 * wv.z; acc[3][3] += x3 * wv.w;
    }
  }
  for (int j = 0; j < 4; ++j) {
    int r = r0 + ty * 4 + j;
    if (r < N_NODES) {
      ushort4 o;
      o.x = f2bf(acc[j][0]); o.y = f2bf(acc[j][1]);
      o.z = f2bf(acc[j][2]); o.w = f2bf(acc[j][3]);
      *(ushort4*)&C[(long)r * 128 + tx * 4] = o;
    }
  }
}

// ---------------------------------------------------------------------------
// Scan chain for CSR rowptr (+cursor init)
// ---------------------------------------------------------------------------
__global__ __launch_bounds__(256) void blocksum_kernel(
    const int* __restrict__ cnt, int* __restrict__ bsum) {
  int idx = blockIdx.x * 256 + threadIdx.x;
  int v = (idx < N_NODES) ? cnt[idx] : 0;
  __shared__ int sc[256];
  sc[threadIdx.x] = v;
  __syncthreads();
  for (int off = 128; off > 0; off >>= 1) {
    if (threadIdx.x < off) sc[threadIdx.x] += sc[threadIdx.x + off];
    __syncthreads();
  }
  if (threadIdx.x == 0) bsum[blockIdx.x] = sc[0];
}

__global__ __launch_bounds__(256) void scanb_kernel(
    const int* __restrict__ bsum, int* __restrict__ boff, int nb) {
  int t = threadIdx.x;
  int v = (t < nb) ? bsum[t] : 0;
  __shared__ int sc[256];
  sc[t] = v;
  __syncthreads();
  for (int off = 1; off < 256; off <<= 1) {
    int x = (t >= off) ? sc[t - off] : 0;
    __syncthreads();
    sc[t] += x;
    __syncthreads();
  }
  if (t < nb) boff[t] = sc[t] - v;  // exclusive
}

__global__ __launch_bounds__(256) void expand_kernel(
    const int* __restrict__ cnt, const int* __restrict__ boff,
    int* __restrict__ rowptr, int* __restrict__ cursor) {
  int t = threadIdx.x;
  int idx = blockIdx.x * 256 + t;
  int v = (idx < N_NODES) ? cnt[idx] : 0;
  __shared__ int sc[256];
  sc[t] = v;
  __syncthreads();
  for (int off = 1; off < 256; off <<= 1) {
    int x = (t >= off) ? sc[t - off] : 0;
    __syncthreads();
    sc[t] += x;
    __syncthreads();
  }
  if (idx < N_NODES) {
    int pfx = boff[blockIdx.x] + sc[t] - v;
    rowptr[idx] = pfx;
    cursor[idx] = pfx;
  }
  if (idx == 0) rowptr[N_NODES] = NEDGE;
}

// ---------------------------------------------------------------------------
// Partitioned place: block (p,chunk) scatters only rows of partition p.
// cursor atomics and ep writes are partition-exclusive -> XCD-local.
// ---------------------------------------------------------------------------
__global__ __launch_bounds__(256) void place_part_kernel(
    const int4* __restrict__ row4, const int4* __restrict__ col4,
    const float4* __restrict__ vals4, int* __restrict__ cursor,
    unsigned* __restrict__ ep) {
  const int t = threadIdx.x;
  const int p = blockIdx.x & 7;
  const int chunk = blockIdx.x >> 3;
  const int lo = p * PR;
  for (int i = t; i < 2048; i += 256) {
    int idx = chunk * 2048 + i;
    if (idx >= NEDGE / 4) break;
    int4 r = row4[idx];
    int4 c = col4[idx];
    float4 v = vals4[idx];
    if ((unsigned)(r.x - lo) < PR) {
      int pos = atomicAdd(&cursor[r.x], 1);
      ep[pos] = ((unsigned)c.x << 16) | f2bf(v.x);
    }
    if ((unsigned)(r.y - lo) < PR) {
      int pos = atomicAdd(&cursor[r.y], 1);
      ep[pos] = ((unsigned)c.y << 16) | f2bf(v.y);
    }
    if ((unsigned)(r.z - lo) < PR) {
      int pos = atomicAdd(&cursor[r.z], 1);
      ep[pos] = ((unsigned)c.z << 16) | f2bf(v.z);
    }
    if ((unsigned)(r.w - lo) < PR) {
      int pos = atomicAdd(&cursor[r.w], 1);
      ep[pos] = ((unsigned)c.w << 16) | f2bf(v.w);
    }
  }
}

// ---------------------------------------------------------------------------
// Gather-SpMM 128 feats + fused stats partials, row-partition swizzled.
// ---------------------------------------------------------------------------
__global__ __launch_bounds__(256) void gather128s_kernel(
    const int* __restrict__ rowptr, const unsigned* __restrict__ ep,
    const ushort* __restrict__ S, ushort2* __restrict__ H,
    float* __restrict__ part_s, float* __restrict__ part_q) {
  const int t = threadIdx.x;
  const int lane = t & 63;
  const int wv = t >> 6;  // 0..3
  const int p = blockIdx.x & 7;
  const int pb = blockIdx.x >> 3;  // 0..255
  const int base = p * PR;
  float cs0 = 0.f, cs1 = 0.f, cq0 = 0.f, cq1 = 0.f;

  for (int local = pb * 4 + wv; local < PR; local += (GB / 8) * 4) {
    int r = base + local;
    int b = rowptr[r], e2 = rowptr[r + 1];
    float a0x = 0.f, a0y = 0.f, a1x = 0.f, a1y = 0.f;
    float a2x = 0.f, a2y = 0.f, a3x = 0.f, a3y = 0.f;
    int e = b;
    for (; e + 3 < e2; e += 4) {
      unsigned u0 = ep[e], u1 = ep[e + 1], u2 = ep[e + 2], u3 = ep[e + 3];
      ushort2 s0 = ((const ushort2*)(S + (long)(u0 >> 16) * 128))[lane];
      ushort2 s1 = ((const ushort2*)(S + (long)(u1 >> 16) * 128))[lane];
      ushort2 s2 = ((const ushort2*)(S + (long)(u2 >> 16) * 128))[lane];
      ushort2 s3 = ((const ushort2*)(S + (long)(u3 >> 16) * 128))[lane];
      float v0 = bf2f((ushort)u0), v1 = bf2f((ushort)u1);
      float v2 = bf2f((ushort)u2), v3 = bf2f((ushort)u3);
      a0x += v0 * bf2f(s0.x); a0y += v0 * bf2f(s0.y);
      a1x += v1 * bf2f(s1.x); a1y += v1 * bf2f(s1.y);
      a2x += v2 * bf2f(s2.x); a2y += v2 * bf2f(s2.y);
      a3x += v3 * bf2f(s3.x); a3y += v3 * bf2f(s3.y);
    }
    for (; e < e2; ++e) {
      unsigned u0 = ep[e];
      float v0 = bf2f((ushort)u0);
      ushort2 s0 = ((const ushort2*)(S + (long)(u0 >> 16) * 128))[lane];
      a0x += v0 * bf2f(s0.x); a0y += v0 * bf2f(s0.y);
    }
    float hx = (a0x + a1x) + (a2x + a3x);
    float hy = (a0y + a1y) + (a2y + a3y);
    ushort2 o = make_ushort2(f2bf(hx), f2bf(hy));
    H[(long)r * 64 + lane] = o;
    float rx = bf2f(o.x), ry = bf2f(o.y);
    cs0 += rx; cq0 += rx * rx;
    cs1 += ry; cq1 += ry * ry;
  }

  __shared__ float lds[4][128];
  lds[wv][lane * 2] = cs0; lds[wv][lane * 2 + 1] = cs1;
  __syncthreads();
  if (t < 128)
    part_s[blockIdx.x * 128 + t] =
        lds[0][t] + lds[1][t] + lds[2][t] + lds[3][t];
  __syncthreads();
  lds[wv][lane * 2] = cq0; lds[wv][lane * 2 + 1] = cq1;
  __syncthreads();
  if (t < 128)
    part_q[blockIdx.x * 128 + t] =
        lds[0][t] + lds[1][t] + lds[2][t] + lds[3][t];
}

// reduce [GB][128] partials -> s,ss
__global__ __launch_bounds__(1024) void reduce128_kernel(
    const float* __restrict__ part_s, const float* __restrict__ part_q,
    float* __restrict__ s, float* __restrict__ ss) {
  int t = threadIdx.x;
  int c = t & 127, sg = t >> 7;
  float a = 0.f, b = 0.f;
  for (int i = sg * 256; i < sg * 256 + 256; ++i) {
    a += part_s[i * 128 + c];
    b += part_q[i * 128 + c];
  }
  __shared__ float la[8][128], lb[8][128];
  la[sg][c] = a; lb[sg][c] = b;
  __syncthreads();
  if (t < 128) {
    float x = 0.f, y = 0.f;
#pragma unroll
    for (int g = 0; g < 8; ++g) { x += la[g][t]; y += lb[g][t]; }
    s[t] = x; ss[t] = y;
  }
}

// ---------------------------------------------------------------------------
// GEMM2: C[N,64](bf16) = relu(bn1(H1 bf16)) @ W2 (f32 math, chunked W)
// ---------------------------------------------------------------------------
__global__ __launch_bounds__(256) void gemm2_kernel(
    const ushort* __restrict__ Hbf, const float4* __restrict__ W4,
    const float* __restrict__ s1, const float* __restrict__ ss1,
    const float* __restrict__ gamma, const float* __restrict__ beta,
    ushort* __restrict__ C) {
  __shared__ float4 sW[64 * 16];   // 16KB
  __shared__ float4 sX[32 * 32];   // 16KB
  __shared__ float sA[128], sB[128];
  const int t = threadIdx.x;

  if (t < 128) {
    float mean = s1[t] * (1.0f / N_NODES);
    float var = ss1[t] * (1.0f / N_NODES) - mean * mean;
    float a = gamma[t] * rsqrtf(var + BN_EPS);
    sA[t] = a;
    sB[t] = beta[t] - a * mean;
  }
  __syncthreads();

  const int r0 = blockIdx.x * 32;
  for (int i = t; i < 1024; i += 256) {
    int rr = i >> 5;
    int r = r0 + rr;
    int c4 = i & 31;
    float4 v = make_float4(0.f, 0.f, 0.f, 0.f);
    if (r < N_NODES) {
      ushort4 u = *(const ushort4*)(Hbf + (long)r * 128 + c4 * 4);
      float4 a4 = *(const float4*)&sA[c4 * 4];
      float4 b4 = *(const float4*)&sB[c4 * 4];
      v.x = fmaxf(a4.x * bf2f(u.x) + b4.x, 0.f);
      v.y = fmaxf(a4.y * bf2f(u.y) + b4.y, 0.f);
      v.z = fmaxf(a4.z * bf2f(u.z) + b4.z, 0.f);
      v.w = fmaxf(a4.w * bf2f(u.w) + b4.w, 0.f);
    }
    sX[i] = v;
  }

  const int tx = t & 15;
  const int ty = t >> 4;
  float acc[2][4] = {{0.f}};
  float* Xl = (float*)sX;

  for (int kt = 0; kt < 2; ++kt) {
    __syncthreads();
    for (int i = t; i < 1024; i += 256) sW[i] = W4[kt * 1024 + i];
    __syncthreads();
    const int kbase = kt * 64;
#pragma unroll 8
    for (int kk = 0; kk < 64; ++kk) {
      float4 wv = sW[kk * 16 + tx];
      float x0 = Xl[(ty * 2 + 0) * 128 + kbase + kk];
      float x1 = Xl[(ty * 2 + 1) * 128 + kbase + kk];
      acc[0][0] += x0 * wv.x; acc[0][1] += x0 * wv.y;
      acc[0][2] += x0 * wv.z; acc[0][3] += x0 * wv.w;
      acc[1][0] += x1 * wv.x; acc[1][1] += x1 * wv.y;
      acc[1][2] += x1 * wv.z; acc[1][3] += x1 * wv.w;
    }
  }
  for (int j = 0; j < 2; ++j) {
    int r = r0 + ty * 2 + j;
    if (r < N_NODES) {
      ushort4 o;
      o.x = f2bf(acc[j][0]); o.y = f2bf(acc[j][1]);
      o.z = f2bf(acc[j][2]); o.w = f2bf(acc[j][3]);
      *(ushort4*)&C[(long)r * 64 + tx * 4] = o;
    }
  }
}

// ---------------------------------------------------------------------------
// Gather-SpMM 64 feats + fused stats partials, row-partition swizzled.
// ---------------------------------------------------------------------------
__global__ __launch_bounds__(256) void gather64s_kernel(
    const int* __restrict__ rowptr, const unsigned* __restrict__ ep,
    const ushort* __restrict__ S, float2* __restrict__ H,
    float* __restrict__ part_s, float* __restrict__ part_q) {
  const int t = threadIdx.x;
  const int sub = t & 31;
  const int rg = t >> 5;  // 0..7
  const int p = blockIdx.x & 7;
  const int pb = blockIdx.x >> 3;  // 0..255
  const int base = p * PR;
  float cs0 = 0.f, cs1 = 0.f, cq0 = 0.f, cq1 = 0.f;

  for (int local = pb * 8 + rg; local < PR; local += (GB / 8) * 8) {
    int r = base + local;
    int b = rowptr[r], e2 = rowptr[r + 1];
    float a0x = 0.f, a0y = 0.f, a1x = 0.f, a1y = 0.f;
    float a2x = 0.f, a2y = 0.f, a3x = 0.f, a3y = 0.f;
    int e = b;
    for (; e + 3 < e2; e += 4) {
      unsigned u0 = ep[e], u1 = ep[e + 1], u2 = ep[e + 2], u3 = ep[e + 3];
      ushort2 s0 = ((const ushort2*)(S + (long)(u0 >> 16) * 64))[sub];
      ushort2 s1 = ((const ushort2*)(S + (long)(u1 >> 16) * 64))[sub];
      ushort2 s2 = ((const ushort2*)(S + (long)(u2 >> 16) * 64))[sub];
      ushort2 s3 = ((const ushort2*)(S + (long)(u3 >> 16) * 64))[sub];
      float v0 = bf2f((ushort)u0), v1 = bf2f((ushort)u1);
      float v2 = bf2f((ushort)u2), v3 = bf2f((ushort)u3);
      a0x += v0 * bf2f(s0.x); a0y += v0 * bf2f(s0.y);
      a1x += v1 * bf2f(s1.x); a1y += v1 * bf2f(s1.y);
      a2x += v2 * bf2f(s2.x); a2y += v2 * bf2f(s2.y);
      a3x += v3 * bf2f(s3.x); a3y += v3 * bf2f(s3.y);
    }
    for (; e < e2; ++e) {
      unsigned u0 = ep[e];
      float v0 = bf2f((ushort)u0);
      ushort2 s0 = ((const ushort2*)(S + (long)(u0 >> 16) * 64))[sub];
      a0x += v0 * bf2f(s0.x); a0y += v0 * bf2f(s0.y);
    }
    float hx = (a0x + a1x) + (a2x + a3x);
    float hy = (a0y + a1y) + (a2y + a3y);
    H[(long)r * 32 + sub] = make_float2(hx, hy);
    cs0 += hx; cq0 += hx * hx;
    cs1 += hy; cq1 += hy * hy;
  }

  __shared__ float lds[8][64];
  lds[rg][sub * 2] = cs0; lds[rg][sub * 2 + 1] = cs1;
  __syncthreads();
  if (t < 64) {
    float x = 0.f;
#pragma unroll
    for (int g = 0; g < 8; ++g) x += lds[g][t];
    part_s[blockIdx.x * 64 + t] = x;
  }
  __syncthreads();
  lds[rg][sub * 2] = cq0; lds[rg][sub * 2 + 1] = cq1;
  __syncthreads();
  if (t < 64) {
    float x = 0.f;
#pragma unroll
    for (int g = 0; g < 8; ++g) x += lds[g][t];
    part_q[blockIdx.x * 64 + t] = x;
  }
}

// reduce [GB][64] partials -> s,ss
__global__ __launch_bounds__(512) void reduce64_kernel(
    const float* __restrict__ part_s, const float* __restrict__ part_q,
    float* __restrict__ s, float* __restrict__ ss) {
  int t = threadIdx.x;
  int c = t & 63, sg = t >> 6;
  float a = 0.f, b = 0.f;
  for (int i = sg * 256; i < sg * 256 + 256; ++i) {
    a += part_s[i * 64 + c];
    b += part_q[i * 64 + c];
  }
  __shared__ float la[8][64], lb[8][64];
  la[sg][c] = a; lb[sg][c] = b;
  __syncthreads();
  if (t < 64) {
    float x = 0.f, y = 0.f;
#pragma unroll
    for (int g = 0; g < 8; ++g) { x += la[g][t]; y += lb[g][t]; }
    s[t] = x; ss[t] = y;
  }
}

// ---------------------------------------------------------------------------
// Final partials: partF[b][c] = sum_r relu(bn2(H2[r][c])) * Wm[r][c]
// ---------------------------------------------------------------------------
__global__ __launch_bounds__(256) void final_part_kernel(
    const float* __restrict__ H, const float* __restrict__ Wm,
    const float* __restrict__ s2, const float* __restrict__ ss2,
    const float* __restrict__ gamma, const float* __restrict__ beta,
    float* __restrict__ partF) {
  const int t = threadIdx.x;
  const int c = t & 63;
  const int rg = t >> 6;
  float mean = s2[c] * (1.0f / N_NODES);
  float var = ss2[c] * (1.0f / N_NODES) - mean * mean;
  float a = gamma[c] * rsqrtf(var + BN_EPS);
  float b = beta[c] - a * mean;
  float sum = 0.f;
  for (int r = blockIdx.x * 4 + rg; r < N_NODES; r += FB * 4) {
    float x = fmaxf(a * H[(long)r * 64 + c] + b, 0.f);
    sum += x * Wm[(long)r * 64 + c];
  }
  __shared__ float lds[4][64];
  lds[rg][c] = sum;
  __syncthreads();
  if (t < 64)
    partF[blockIdx.x * 64 + t] =
        lds[0][t] + lds[1][t] + lds[2][t] + lds[3][t];
}

__global__ void writeout_kernel(const float* __restrict__ partF,
                                const float* __restrict__ bm,
                                float* __restrict__ out) {
  int t = threadIdx.x;  // 64 threads
  float x = bm[t];
  for (int i = 0; i < FB; ++i) x += partF[i * 64 + t];
  out[t] = 1.0f / (1.0f + expf(-x));
}

// ---------------------------------------------------------------------------
extern "C" void kernel_launch(void* const* d_in, const int* in_sizes, int n_in,
                              void* d_out, int out_size, void* d_ws,
                              size_t ws_size, hipStream_t stream) {
  const float* emb  = (const float*)d_in[0];
  const float* W1   = (const float*)d_in[1];
  // d_in[2] = b1: cancels exactly under BN
  const float* g1   = (const float*)d_in[3];
  const float* be1  = (const float*)d_in[4];
  const float* W2   = (const float*)d_in[5];
  // d_in[6] = b2: cancels under BN
  const float* g2   = (const float*)d_in[7];
  const float* be2  = (const float*)d_in[8];
  const float* Wm   = (const float*)d_in[9];
  const float* bm   = (const float*)d_in[10];
  // d_in[11] = vertices = arange(N): identity gather
  const int* row    = (const int*)d_in[12];
  const int* col    = (const int*)d_in[13];
  const float* vals = (const float*)d_in[14];

  // workspace layout
  ushort*   sup    = (ushort*)d_ws;              // 6.4M bf16 (12.8 MB)
  ushort*   h1     = sup + 6400000;              // 6.4M bf16 (12.8 MB)
  float*    h2     = (float*)(h1 + 6400000);     // 3.2M f32 (12.8 MB)
  unsigned* ep     = (unsigned*)(h2 + 3200000);  // 1.6M u32 (6.4 MB)
  int*      rowptr = (int*)(ep + 1600000);       // 50,001
  int*      cursor = rowptr + 50001;             // 50,000
  int*      cnt    = cursor + 50000;             // 50,000
  int*      bsum   = cnt + 50000;                // 256
  int*      boff   = bsum + 256;                 // 256
  float*    part_s = (float*)(boff + 256);       // GB*128 (1 MB)
  float*    part_q = part_s + GB * 128;          // GB*128 (1 MB)
  float*    s1     = part_q + GB * 128;          // 128
  float*    ss1    = s1 + 128;                   // 128
  float*    s2     = ss1 + 128;                  // 64
  float*    ss2    = s2 + 64;                    // 64
  float*    partF  = part_s;                     // FB*64 alias (free by then)
  float*    out = (float*)d_out;

  const int NB = (N_NODES + 255) / 256;  // 196

  hipMemsetAsync(cnt, 0, N_NODES * sizeof(int), stream);

  // ---- partitioned hist + gemm1 fused ----
  hist_gemm1_kernel<<<HB + G1_BLOCKS, 256, 0, stream>>>(
      (const int4*)row, cnt, (const float4*)emb, (const float4*)W1, sup);

  // ---- rowptr scan (+cursor init) ----
  blocksum_kernel<<<NB, 256, 0, stream>>>(cnt, bsum);
  scanb_kernel<<<1, 256, 0, stream>>>(bsum, boff, NB);
  expand_kernel<<<NB, 256, 0, stream>>>(cnt, boff, rowptr, cursor);

  // ---- partitioned place ----
  place_part_kernel<<<HB, 256, 0, stream>>>(
      (const int4*)row, (const int4*)col, (const float4*)vals, cursor, ep);

  // ---- Layer 1 aggregate + fused stats ----
  gather128s_kernel<<<GB, 256, 0, stream>>>(rowptr, ep, sup, (ushort2*)h1,
                                            part_s, part_q);
  reduce128_kernel<<<1, 1024, 0, stream>>>(part_s, part_q, s1, ss1);

  // ---- Layer 2 ----
  gemm2_kernel<<<G1_BLOCKS, 256, 0, stream>>>(h1, (const float4*)W2, s1, ss1,
                                              g1, be1, sup);
  gather64s_kernel<<<GB, 256, 0, stream>>>(rowptr, ep, sup, (float2*)h2,
                                           part_s, part_q);
  reduce64_kernel<<<1, 512, 0, stream>>>(part_s, part_q, s2, ss2);

  // ---- MaskLinear + sigmoid ----
  final_part_kernel<<<FB, 256, 0, stream>>>(h2, Wm, s2, ss2, g2, be2, partF);
  writeout_kernel<<<1, 64, 0, stream>>>(partF, bm, out);
}

// Round 10
// 355.189 us; speedup vs baseline: 1.1804x; 1.1804x over previous
//
#include <hip/hip_runtime.h>
#include <hip/hip_bf16.h>
#include <math.h>

#define N_NODES 50000
#define NEDGE 1600000
#define BN_EPS 1e-5f
#define EB 1563         // ceil((NEDGE/4)/256) edge chunks
#define G1_BLOCKS 1563  // ceil(50000/32) gemm1 tiles
#define SB 128          // partial-reduction blocks

__device__ inline float bf2f(ushort u) {
  union { unsigned i; float f; } v;
  v.i = ((unsigned)u) << 16;
  return v.f;
}
__device__ inline ushort f2bf(float x) {
  __hip_bfloat16 b = __float2bfloat16(x);
  return *(ushort*)&b;
}

// ---------------------------------------------------------------------------
// Rank: atomic histogram + stable per-row rank of edges (no LDS, high occ)
// ---------------------------------------------------------------------------
__global__ __launch_bounds__(256) void rank_kernel(
    const int4* __restrict__ row4, int* __restrict__ cnt,
    ushort* __restrict__ rank) {
  int i = blockIdx.x * 256 + threadIdx.x;
  if (i >= NEDGE / 4) return;
  int4 r = row4[i];
  ushort4 rk;
  rk.x = (ushort)atomicAdd(&cnt[r.x], 1);
  rk.y = (ushort)atomicAdd(&cnt[r.y], 1);
  rk.z = (ushort)atomicAdd(&cnt[r.z], 1);
  rk.w = (ushort)atomicAdd(&cnt[r.w], 1);
  ((ushort4*)rank)[i] = rk;
}

// ---------------------------------------------------------------------------
// Scan chain for CSR rowptr
// ---------------------------------------------------------------------------
__global__ __launch_bounds__(256) void blocksum_kernel(
    const int* __restrict__ cnt, int* __restrict__ bsum) {
  int idx = blockIdx.x * 256 + threadIdx.x;
  int v = (idx < N_NODES) ? cnt[idx] : 0;
  __shared__ int sc[256];
  sc[threadIdx.x] = v;
  __syncthreads();
  for (int off = 128; off > 0; off >>= 1) {
    if (threadIdx.x < off) sc[threadIdx.x] += sc[threadIdx.x + off];
    __syncthreads();
  }
  if (threadIdx.x == 0) bsum[blockIdx.x] = sc[0];
}

__global__ __launch_bounds__(256) void scanb_kernel(
    const int* __restrict__ bsum, int* __restrict__ boff, int nb) {
  int t = threadIdx.x;
  int v = (t < nb) ? bsum[t] : 0;
  __shared__ int sc[256];
  sc[t] = v;
  __syncthreads();
  for (int off = 1; off < 256; off <<= 1) {
    int x = (t >= off) ? sc[t - off] : 0;
    __syncthreads();
    sc[t] += x;
    __syncthreads();
  }
  if (t < nb) boff[t] = sc[t] - v;  // exclusive
}

__global__ __launch_bounds__(256) void expand_kernel(
    const int* __restrict__ cnt, const int* __restrict__ boff,
    int* __restrict__ rowptr) {
  int t = threadIdx.x;
  int idx = blockIdx.x * 256 + t;
  int v = (idx < N_NODES) ? cnt[idx] : 0;
  __shared__ int sc[256];
  sc[t] = v;
  __syncthreads();
  for (int off = 1; off < 256; off <<= 1) {
    int x = (t >= off) ? sc[t - off] : 0;
    __syncthreads();
    sc[t] += x;
    __syncthreads();
  }
  if (idx < N_NODES) rowptr[idx] = boff[blockIdx.x] + sc[t] - v;
  if (idx == 0) rowptr[N_NODES] = NEDGE;
}

// ---------------------------------------------------------------------------
// Fused: even blocks -> place edge chunk (no atomics, rank precomputed);
//        odd blocks  -> GEMM1 32-row tile (f32 math, bf16 out). Independent.
// ---------------------------------------------------------------------------
__global__ __launch_bounds__(256) void place_gemm1_kernel(
    const int4* __restrict__ row4, const int4* __restrict__ col4,
    const float4* __restrict__ vals4, const ushort* __restrict__ rank,
    const int* __restrict__ rowptr, unsigned* __restrict__ ep,
    const float4* __restrict__ X4, const float4* __restrict__ W4,
    ushort* __restrict__ C) {
  __shared__ float4 sW[64 * 32];   // 32KB
  __shared__ float4 sX[32 * 32];   // 16KB
  const int t = threadIdx.x;

  if (!(blockIdx.x & 1)) {  // ---- place part ----
    int i = (blockIdx.x >> 1) * 256 + t;
    if (i < NEDGE / 4) {
      int4 r = row4[i];
      int4 c = col4[i];
      float4 v = vals4[i];
      ushort4 rk = ((const ushort4*)rank)[i];
      ep[rowptr[r.x] + rk.x] = ((unsigned)c.x << 16) | f2bf(v.x);
      ep[rowptr[r.y] + rk.y] = ((unsigned)c.y << 16) | f2bf(v.y);
      ep[rowptr[r.z] + rk.z] = ((unsigned)c.z << 16) | f2bf(v.z);
      ep[rowptr[r.w] + rk.w] = ((unsigned)c.w << 16) | f2bf(v.w);
    }
    return;
  }

  // ---- gemm1 part ----
  float* Xl = (float*)sX;
  const int r0 = (blockIdx.x >> 1) * 32;

  for (int i = t; i < 1024; i += 256) {
    int rr = i >> 5;
    int r = r0 + rr;
    sX[i] = (r < N_NODES) ? X4[(long)r * 32 + (i & 31)]
                          : make_float4(0.f, 0.f, 0.f, 0.f);
  }

  const int tx = t & 31;
  const int ty = t >> 5;
  float acc[4][4] = {{0.f}};

  for (int kt = 0; kt < 2; ++kt) {
    __syncthreads();
    for (int i = t; i < 2048; i += 256) sW[i] = W4[kt * 2048 + i];
    __syncthreads();
    const int kbase = kt * 64;
#pragma unroll 8
    for (int kk = 0; kk < 64; ++kk) {
      float4 wv = sW[kk * 32 + tx];
      float x0 = Xl[(ty * 4 + 0) * 128 + kbase + kk];
      float x1 = Xl[(ty * 4 + 1) * 128 + kbase + kk];
      float x2 = Xl[(ty * 4 + 2) * 128 + kbase + kk];
      float x3 = Xl[(ty * 4 + 3) * 128 + kbase + kk];
      acc[0][0] += x0 * wv.x; acc[0][1] += x0 * wv.y;
      acc[0][2] += x0 * wv.z; acc[0][3] += x0 * wv.w;
      acc[1][0] += x1 * wv.x; acc[1][1] += x1 * wv.y;
      acc[1][2] += x1 * wv.z; acc[1][3] += x1 * wv.w;
      acc[2][0] += x2 * wv.x; acc[2][1] += x2 * wv.y;
      acc[2][2] += x2 * wv.z; acc[2][3] += x2 * wv.w;
      acc[3][0] += x3 * wv.x; acc[3][1] += x3 * wv.y;
      acc[3][2] += x3 * wv.z; acc[3][3] += x3 * wv.w;
    }
  }
  for (int j = 0; j < 4; ++j) {
    int r = r0 + ty * 4 + j;
    if (r < N_NODES) {
      ushort4 o;
      o.x = f2bf(acc[j][0]); o.y = f2bf(acc[j][1]);
      o.z = f2bf(acc[j][2]); o.w = f2bf(acc[j][3]);
      *(ushort4*)&C[(long)r * 128 + tx * 4] = o;
    }
  }
}

// ---------------------------------------------------------------------------
// Gather-SpMM, 128 feats: one wave per row, unroll-8 edges, bf16 in/out.
// ---------------------------------------------------------------------------
__global__ __launch_bounds__(256) void gather128_kernel(
    const int* __restrict__ rowptr, const unsigned* __restrict__ ep,
    const ushort* __restrict__ S, ushort2* __restrict__ H) {
  int r = (blockIdx.x * 256 + threadIdx.x) >> 6;
  int lane = threadIdx.x & 63;
  if (r >= N_NODES) return;
  int b = rowptr[r], e2 = rowptr[r + 1];
  float ax[8], ay[8];
#pragma unroll
  for (int i = 0; i < 8; ++i) { ax[i] = 0.f; ay[i] = 0.f; }
  int e = b;
  for (; e + 7 < e2; e += 8) {
    unsigned u[8];
    ushort2 s[8];
#pragma unroll
    for (int i = 0; i < 8; ++i) u[i] = ep[e + i];
#pragma unroll
    for (int i = 0; i < 8; ++i)
      s[i] = ((const ushort2*)(S + (long)(u[i] >> 16) * 128))[lane];
#pragma unroll
    for (int i = 0; i < 8; ++i) {
      float v = bf2f((ushort)u[i]);
      ax[i] += v * bf2f(s[i].x);
      ay[i] += v * bf2f(s[i].y);
    }
  }
  for (; e < e2; ++e) {
    unsigned u0 = ep[e];
    float v0 = bf2f((ushort)u0);
    ushort2 s0 = ((const ushort2*)(S + (long)(u0 >> 16) * 128))[lane];
    ax[0] += v0 * bf2f(s0.x);
    ay[0] += v0 * bf2f(s0.y);
  }
  float hx = ((ax[0] + ax[1]) + (ax[2] + ax[3])) +
             ((ax[4] + ax[5]) + (ax[6] + ax[7]));
  float hy = ((ay[0] + ay[1]) + (ay[2] + ay[3])) +
             ((ay[4] + ay[5]) + (ay[6] + ay[7]));
  H[(long)r * 64 + lane] = make_ushort2(f2bf(hx), f2bf(hy));
}

// ---------------------------------------------------------------------------
// Stats over bf16 H1: block partials + last-block reduce -> s1,ss1
// ---------------------------------------------------------------------------
__global__ __launch_bounds__(256) void statsbf_kernel(
    const ushort* __restrict__ H, float* __restrict__ part_s,
    float* __restrict__ part_q, int* __restrict__ ticket,
    float* __restrict__ s, float* __restrict__ ss) {
  const int t = threadIdx.x;
  const int cg = t & 31;   // col group of 4
  const int rg = t >> 5;   // 0..7
  float sum0 = 0.f, sum1 = 0.f, sum2 = 0.f, sum3 = 0.f;
  float sq0 = 0.f, sq1 = 0.f, sq2 = 0.f, sq3 = 0.f;
  for (int r = blockIdx.x * 8 + rg; r < N_NODES; r += SB * 8) {
    ushort4 u = *(const ushort4*)(H + (long)r * 128 + cg * 4);
    float x0 = bf2f(u.x), x1 = bf2f(u.y), x2 = bf2f(u.z), x3 = bf2f(u.w);
    sum0 += x0; sq0 += x0 * x0;
    sum1 += x1; sq1 += x1 * x1;
    sum2 += x2; sq2 += x2 * x2;
    sum3 += x3; sq3 += x3 * x3;
  }
  __shared__ float lds[8][128];
  lds[rg][cg * 4 + 0] = sum0; lds[rg][cg * 4 + 1] = sum1;
  lds[rg][cg * 4 + 2] = sum2; lds[rg][cg * 4 + 3] = sum3;
  __syncthreads();
  if (t < 128) {
    float x = 0.f;
#pragma unroll
    for (int g = 0; g < 8; ++g) x += lds[g][t];
    part_s[blockIdx.x * 128 + t] = x;
  }
  __syncthreads();
  lds[rg][cg * 4 + 0] = sq0; lds[rg][cg * 4 + 1] = sq1;
  lds[rg][cg * 4 + 2] = sq2; lds[rg][cg * 4 + 3] = sq3;
  __syncthreads();
  if (t < 128) {
    float x = 0.f;
#pragma unroll
    for (int g = 0; g < 8; ++g) x += lds[g][t];
    part_q[blockIdx.x * 128 + t] = x;
  }
  // last block reduces
  __shared__ bool isLast;
  __threadfence();
  if (t == 0) isLast = (atomicAdd(ticket, 1) == SB - 1);
  __syncthreads();
  if (isLast && t < 128) {
    float a = 0.f, bq = 0.f;
    for (int i = 0; i < SB; ++i) {
      a += part_s[i * 128 + t];
      bq += part_q[i * 128 + t];
    }
    s[t] = a;
    ss[t] = bq;
  }
}

// ---------------------------------------------------------------------------
// GEMM2: C[N,64](bf16) = relu(bn1(H1[N,128](bf16))) @ W2[128,64]
// ---------------------------------------------------------------------------
__global__ __launch_bounds__(256) void gemm2_kernel(
    const ushort* __restrict__ Hbf, const float4* __restrict__ W4,
    const float* __restrict__ s1, const float* __restrict__ ss1,
    const float* __restrict__ gamma, const float* __restrict__ beta,
    ushort* __restrict__ C) {
  __shared__ float4 sW[128 * 16];  // 32KB
  __shared__ float4 sX[32 * 32];   // 16KB
  __shared__ float sA[128], sB[128];
  const int t = threadIdx.x;

  if (t < 128) {
    float mean = s1[t] * (1.0f / N_NODES);
    float var = ss1[t] * (1.0f / N_NODES) - mean * mean;
    float a = gamma[t] * rsqrtf(var + BN_EPS);
    sA[t] = a;
    sB[t] = beta[t] - a * mean;
  }
  for (int i = t; i < 2048; i += 256) sW[i] = W4[i];
  __syncthreads();

  const int r0 = blockIdx.x * 32;
  for (int i = t; i < 1024; i += 256) {
    int rr = i >> 5;
    int r = r0 + rr;
    int c4 = i & 31;
    float4 v = make_float4(0.f, 0.f, 0.f, 0.f);
    if (r < N_NODES) {
      ushort4 u = *(const ushort4*)(Hbf + (long)r * 128 + c4 * 4);
      float4 a4 = *(const float4*)&sA[c4 * 4];
      float4 b4 = *(const float4*)&sB[c4 * 4];
      v.x = fmaxf(a4.x * bf2f(u.x) + b4.x, 0.f);
      v.y = fmaxf(a4.y * bf2f(u.y) + b4.y, 0.f);
      v.z = fmaxf(a4.z * bf2f(u.z) + b4.z, 0.f);
      v.w = fmaxf(a4.w * bf2f(u.w) + b4.w, 0.f);
    }
    sX[i] = v;
  }
  __syncthreads();

  const int tx = t & 15;
  const int ty = t >> 4;
  float acc[2][4] = {{0.f}};
  float* Xl = (float*)sX;
#pragma unroll 8
  for (int k = 0; k < 128; ++k) {
    float4 wv = sW[k * 16 + tx];
    float x0 = Xl[(ty * 2 + 0) * 128 + k];
    float x1 = Xl[(ty * 2 + 1) * 128 + k];
    acc[0][0] += x0 * wv.x; acc[0][1] += x0 * wv.y;
    acc[0][2] += x0 * wv.z; acc[0][3] += x0 * wv.w;
    acc[1][0] += x1 * wv.x; acc[1][1] += x1 * wv.y;
    acc[1][2] += x1 * wv.z; acc[1][3] += x1 * wv.w;
  }
  for (int j = 0; j < 2; ++j) {
    int r = r0 + ty * 2 + j;
    if (r < N_NODES) {
      ushort4 o;
      o.x = f2bf(acc[j][0]); o.y = f2bf(acc[j][1]);
      o.z = f2bf(acc[j][2]); o.w = f2bf(acc[j][3]);
      *(ushort4*)&C[(long)r * 64 + tx * 4] = o;
    }
  }
}

// ---------------------------------------------------------------------------
// Gather-SpMM, 64 feats: half-wave per row, unroll-4, bf16 src, f32 out.
// ---------------------------------------------------------------------------
__global__ __launch_bounds__(256) void gather64_kernel(
    const int* __restrict__ rowptr, const unsigned* __restrict__ ep,
    const ushort* __restrict__ S, float2* __restrict__ H) {
  int r = (blockIdx.x * 256 + threadIdx.x) >> 5;
  int sub = threadIdx.x & 31;
  if (r >= N_NODES) return;
  int b = rowptr[r], e2 = rowptr[r + 1];
  float ax[4], ay[4];
#pragma unroll
  for (int i = 0; i < 4; ++i) { ax[i] = 0.f; ay[i] = 0.f; }
  int e = b;
  for (; e + 3 < e2; e += 4) {
    unsigned u[4];
    ushort2 s[4];
#pragma unroll
    for (int i = 0; i < 4; ++i) u[i] = ep[e + i];
#pragma unroll
    for (int i = 0; i < 4; ++i)
      s[i] = ((const ushort2*)(S + (long)(u[i] >> 16) * 64))[sub];
#pragma unroll
    for (int i = 0; i < 4; ++i) {
      float v = bf2f((ushort)u[i]);
      ax[i] += v * bf2f(s[i].x);
      ay[i] += v * bf2f(s[i].y);
    }
  }
  for (; e < e2; ++e) {
    unsigned u0 = ep[e];
    float v0 = bf2f((ushort)u0);
    ushort2 s0 = ((const ushort2*)(S + (long)(u0 >> 16) * 64))[sub];
    ax[0] += v0 * bf2f(s0.x);
    ay[0] += v0 * bf2f(s0.y);
  }
  H[(long)r * 32 + sub] = make_float2((ax[0] + ax[1]) + (ax[2] + ax[3]),
                                      (ay[0] + ay[1]) + (ay[2] + ay[3]));
}

// ---------------------------------------------------------------------------
// Stats over f32 H2: block partials + last-block reduce -> s2,ss2
// ---------------------------------------------------------------------------
__global__ __launch_bounds__(256) void stats64_kernel(
    const float* __restrict__ H, float* __restrict__ part_s,
    float* __restrict__ part_q, int* __restrict__ ticket,
    float* __restrict__ s, float* __restrict__ ss) {
  const int t = threadIdx.x;
  const int c = t & 63;
  const int rg = t >> 6;  // 0..3
  float sum = 0.f, sq = 0.f;
  for (int r = blockIdx.x * 4 + rg; r < N_NODES; r += SB * 4) {
    float x = H[(long)r * 64 + c];
    sum += x;
    sq += x * x;
  }
  __shared__ float lds[4][64];
  lds[rg][c] = sum;
  __syncthreads();
  if (t < 64)
    part_s[blockIdx.x * 64 + t] =
        lds[0][t] + lds[1][t] + lds[2][t] + lds[3][t];
  __syncthreads();
  lds[rg][c] = sq;
  __syncthreads();
  if (t < 64)
    part_q[blockIdx.x * 64 + t] =
        lds[0][t] + lds[1][t] + lds[2][t] + lds[3][t];
  __shared__ bool isLast;
  __threadfence();
  if (t == 0) isLast = (atomicAdd(ticket, 1) == SB - 1);
  __syncthreads();
  if (isLast && t < 64) {
    float a = 0.f, bq = 0.f;
    for (int i = 0; i < SB; ++i) {
      a += part_s[i * 64 + t];
      bq += part_q[i * 64 + t];
    }
    s[t] = a;
    ss[t] = bq;
  }
}

// ---------------------------------------------------------------------------
// Final: partials + last-block reduce + bias + sigmoid -> out
// ---------------------------------------------------------------------------
__global__ __launch_bounds__(256) void final_kernel(
    const float* __restrict__ H, const float* __restrict__ Wm,
    const float* __restrict__ s2, const float* __restrict__ ss2,
    const float* __restrict__ gamma, const float* __restrict__ beta,
    const float* __restrict__ bm, float* __restrict__ partF,
    int* __restrict__ ticket, float* __restrict__ out) {
  const int t = threadIdx.x;
  const int c = t & 63;
  const int rg = t >> 6;
  float mean = s2[c] * (1.0f / N_NODES);
  float var = ss2[c] * (1.0f / N_NODES) - mean * mean;
  float a = gamma[c] * rsqrtf(var + BN_EPS);
  float b = beta[c] - a * mean;
  float sum = 0.f;
  for (int r = blockIdx.x * 4 + rg; r < N_NODES; r += SB * 4) {
    float x = fmaxf(a * H[(long)r * 64 + c] + b, 0.f);
    sum += x * Wm[(long)r * 64 + c];
  }
  __shared__ float lds[4][64];
  lds[rg][c] = sum;
  __syncthreads();
  if (t < 64)
    partF[blockIdx.x * 64 + t] =
        lds[0][t] + lds[1][t] + lds[2][t] + lds[3][t];
  __shared__ bool isLast;
  __threadfence();
  if (t == 0) isLast = (atomicAdd(ticket, 1) == SB - 1);
  __syncthreads();
  if (isLast && t < 64) {
    float x = bm[t];
    for (int i = 0; i < SB; ++i) x += partF[i * 64 + t];
    out[t] = 1.0f / (1.0f + expf(-x));
  }
}

// ---------------------------------------------------------------------------
extern "C" void kernel_launch(void* const* d_in, const int* in_sizes, int n_in,
                              void* d_out, int out_size, void* d_ws,
                              size_t ws_size, hipStream_t stream) {
  const float* emb  = (const float*)d_in[0];
  const float* W1   = (const float*)d_in[1];
  // d_in[2] = b1: cancels exactly under BN
  const float* g1   = (const float*)d_in[3];
  const float* be1  = (const float*)d_in[4];
  const float* W2   = (const float*)d_in[5];
  // d_in[6] = b2: cancels under BN
  const float* g2   = (const float*)d_in[7];
  const float* be2  = (const float*)d_in[8];
  const float* Wm   = (const float*)d_in[9];
  const float* bm   = (const float*)d_in[10];
  // d_in[11] = vertices = arange(N): identity gather
  const int* row    = (const int*)d_in[12];
  const int* col    = (const int*)d_in[13];
  const float* vals = (const float*)d_in[14];

  // workspace layout
  ushort*   sup    = (ushort*)d_ws;              // 6.4M bf16 (12.8 MB)
  ushort*   h1     = sup + 6400000;              // 6.4M bf16 (12.8 MB)
  float*    h2     = (float*)(h1 + 6400000);     // 3.2M f32 (12.8 MB)
  unsigned* ep     = (unsigned*)(h2 + 3200000);  // 1.6M u32 (6.4 MB)
  ushort*   rank   = (ushort*)(ep + 1600000);    // 1.6M u16 (3.2 MB)
  int*      rowptr = (int*)(rank + 1600000);     // 50,001
  int*      cnt    = rowptr + 50001;             // 50,000
  int*      tick   = cnt + 50000;                // 8 (tickets, zeroed w/ cnt)
  int*      bsum   = tick + 8;                   // 256
  int*      boff   = bsum + 256;                 // 256
  float*    part_s = (float*)(boff + 256);       // SB*128
  float*    part_q = part_s + SB * 128;          // SB*128
  float*    partF  = part_q + SB * 128;          // SB*64
  float*    s1     = partF + SB * 64;            // 128
  float*    ss1    = s1 + 128;                   // 128
  float*    s2     = ss1 + 128;                  // 64
  float*    ss2    = s2 + 64;                    // 64
  float*    out = (float*)d_out;

  const int NB = (N_NODES + 255) / 256;  // 196

  hipMemsetAsync(cnt, 0, (50000 + 8) * sizeof(int), stream);

  // ---- rank (standalone, no LDS) ----
  rank_kernel<<<EB, 256, 0, stream>>>((const int4*)row, cnt, rank);

  // ---- rowptr scan ----
  blocksum_kernel<<<NB, 256, 0, stream>>>(cnt, bsum);
  scanb_kernel<<<1, 256, 0, stream>>>(bsum, boff, NB);
  expand_kernel<<<NB, 256, 0, stream>>>(cnt, boff, rowptr);

  // ---- place + gemm1 fused (even=place, odd=gemm1) ----
  place_gemm1_kernel<<<2 * EB, 256, 0, stream>>>(
      (const int4*)row, (const int4*)col, (const float4*)vals, rank, rowptr,
      ep, (const float4*)emb, (const float4*)W1, sup);

  // ---- Layer 1 aggregate + stats ----
  gather128_kernel<<<(N_NODES * 64 + 255) / 256, 256, 0, stream>>>(
      rowptr, ep, sup, (ushort2*)h1);
  statsbf_kernel<<<SB, 256, 0, stream>>>(h1, part_s, part_q, &tick[0], s1,
                                         ss1);

  // ---- Layer 2 ----
  gemm2_kernel<<<G1_BLOCKS, 256, 0, stream>>>(h1, (const float4*)W2, s1, ss1,
                                              g1, be1, sup);
  gather64_kernel<<<(N_NODES * 32 + 255) / 256, 256, 0, stream>>>(
      rowptr, ep, sup, (float2*)h2);
  stats64_kernel<<<SB, 256, 0, stream>>>(h2, part_s, part_q, &tick[1], s2,
                                         ss2);

  // ---- MaskLinear + sigmoid ----
  final_kernel<<<SB, 256, 0, stream>>>(h2, Wm, s2, ss2, g2, be2, bm, partF,
                                       &tick[2], out);
}